// Round 10
// baseline (41.948 us; speedup 1.0000x reference)
//
#include <hip/hip_runtime.h>
#include <math.h>

#define DEPTH    11
#define NNODES   4095
#define DIN      768
#define NTOK     8192
#define TAU      0.06f            // exact-recheck threshold (~7.2 sigma of int8 dot err)
#define WT_MAX   0.12f            // fixed wT quant range (7.7 sigma of N(0,1/sqrt(4095)))
#define WT_STEP  (WT_MAX / 127.0f)

typedef unsigned int uint32;
typedef float f32x4 __attribute__((ext_vector_type(4)));

// ---------------------------------------------------------------------------
// Fused prep: blocks [0,3072) transpose+quantize w_out -> wTq (int8, fixed
// scale); blocks [3072,4096) row-quantize w_in -> wq (int8) + wscale (f32).
// (unchanged from round 8 — proven)
// ---------------------------------------------------------------------------
__global__ __launch_bounds__(256) void fff_prep(const float* __restrict__ w_in,
                                                const float* __restrict__ w_out,
                                                uint32* __restrict__ wq,
                                                float* __restrict__ wscale,
                                                uint32* __restrict__ wTq) {
    __shared__ float tile[32][33];
    const int bid = blockIdx.x;
    const int tid = threadIdx.x;

    if (bid < 3072) {
        const int n0 = (bid & 127) * 32;   // node tile
        const int j0 = (bid >> 7) * 32;    // feature tile (24 tiles)
        const int tx = tid & 31, ty = tid >> 5;  // (32,8)
#pragma unroll
        for (int i = 0; i < 32; i += 8) {
            const int j = j0 + ty + i;
            const int n = n0 + tx;
            if (n < NNODES) tile[ty + i][tx] = w_out[(size_t)j * NNODES + n];
        }
        __syncthreads();
        const int nl = tid >> 3;           // 0..31 node within tile
        const int jq = (tid & 7) * 4;      // 0,4,..,28
        const int n  = n0 + nl;
        if (n < NNODES) {
            const float inv = 127.0f / WT_MAX;
            int q0 = __float2int_rn(fminf(fmaxf(tile[jq + 0][nl] * inv, -127.f), 127.f));
            int q1 = __float2int_rn(fminf(fmaxf(tile[jq + 1][nl] * inv, -127.f), 127.f));
            int q2 = __float2int_rn(fminf(fmaxf(tile[jq + 2][nl] * inv, -127.f), 127.f));
            int q3 = __float2int_rn(fminf(fmaxf(tile[jq + 3][nl] * inv, -127.f), 127.f));
            const uint32 pack = (uint32)(q0 & 0xFF) | ((uint32)(q1 & 0xFF) << 8) |
                                ((uint32)(q2 & 0xFF) << 16) | ((uint32)(q3 & 0xFF) << 24);
            wTq[((size_t)n * DIN + j0 + jq) >> 2] = pack;
        }
    } else {
        const int row  = ((bid - 3072) * 256 + tid) >> 6;
        const int lane = tid & 63;
        if (row < NNODES) {
            const float4* wr = reinterpret_cast<const float4*>(w_in + (size_t)row * DIN);
            const float4 a = wr[lane], b = wr[lane + 64], c = wr[lane + 128];
            float m = fmaxf(fabsf(a.x), fabsf(a.y));
            m = fmaxf(m, fmaxf(fabsf(a.z), fabsf(a.w)));
            m = fmaxf(m, fmaxf(fabsf(b.x), fabsf(b.y)));
            m = fmaxf(m, fmaxf(fabsf(b.z), fabsf(b.w)));
            m = fmaxf(m, fmaxf(fabsf(c.x), fabsf(c.y)));
            m = fmaxf(m, fmaxf(fabsf(c.z), fabsf(c.w)));
#pragma unroll
            for (int off = 32; off >= 1; off >>= 1) m = fmaxf(m, __shfl_xor(m, off));
            const float inv = (m > 0.f) ? (127.0f / m) : 0.f;
            const float s   = m * (1.0f / 127.0f);

            uint32* rq = wq + (size_t)row * (DIN / 4);
            const float4 v[3] = {a, b, c};
#pragma unroll
            for (int k = 0; k < 3; ++k) {
                int q0 = __float2int_rn(fminf(fmaxf(v[k].x * inv, -127.f), 127.f));
                int q1 = __float2int_rn(fminf(fmaxf(v[k].y * inv, -127.f), 127.f));
                int q2 = __float2int_rn(fminf(fmaxf(v[k].z * inv, -127.f), 127.f));
                int q3 = __float2int_rn(fminf(fmaxf(v[k].w * inv, -127.f), 127.f));
                rq[lane + 64 * k] = (uint32)(q0 & 0xFF) | ((uint32)(q1 & 0xFF) << 8) |
                                    ((uint32)(q2 & 0xFF) << 16) | ((uint32)(q3 & 0xFF) << 24);
            }
            if (lane == 0) wscale[row] = s;
        }
    }
}

__device__ __forceinline__ float sb0(uint32 u) { return (float)((int)(u << 24) >> 24); }
__device__ __forceinline__ float sb1(uint32 u) { return (float)((int)(u << 16) >> 24); }
__device__ __forceinline__ float sb2(uint32 u) { return (float)((int)(u <<  8) >> 24); }
__device__ __forceinline__ float sb3(uint32 u) { return (float)((int)u        >> 24); }

// ---------------------------------------------------------------------------
// Walk kernel (int8, L2-resident): touches ONLY wq+wscale (3.16 MB -> fits a
// per-XCD L2). x is read with nontemporal loads so it doesn't evict wq.
// Dual-child speculative prefetch: at L2-hit latency the child loads complete
// under the dot+reduce+gelu of the current level. Rare exact f64 recheck
// (|est| < TAU) keeps decisions on the proven path. Emits bits + g[12].
// Numerics byte-identical to rounds 8/9.
// ---------------------------------------------------------------------------
__global__ __launch_bounds__(256) void fff_walk_i8(const float* __restrict__ x,
                                                   const float* __restrict__ w_in,
                                                   const uint32* __restrict__ wq,
                                                   const float* __restrict__ wscale,
                                                   unsigned* __restrict__ bits_out,
                                                   float* __restrict__ g_out) {
    const int token = (int)((blockIdx.x * blockDim.x + threadIdx.x) >> 6);
    const int lane  = (int)(threadIdx.x & 63);

    // Lane owns elements 4*(lane+64k)+m, k=0..2, m=0..3 (matches packed bytes).
    const f32x4* xr = reinterpret_cast<const f32x4*>(x + (size_t)token * DIN);
    const f32x4 xv0 = __builtin_nontemporal_load(xr + lane);
    const f32x4 xv1 = __builtin_nontemporal_load(xr + lane + 64);
    const f32x4 xv2 = __builtin_nontemporal_load(xr + lane + 128);

    // root row state (node 0)
    int cur = 0;
    uint32 a = wq[lane], b = wq[lane + 64], c = wq[lane + 128];
    float  s = wscale[0];

    unsigned mask = 0;

#pragma unroll
    for (int d = 0; d <= DEPTH; ++d) {
        // ---- (1) prefetch BOTH children dot-rows + scales (L2 hits) ----
        uint32 la = 0, lb = 0, lc = 0, ra = 0, rb = 0, rc = 0;
        float  ls = 0.f, rs = 0.f;
        if (d < DEPTH) {
            const int nl = 2 * cur + 1, nr = 2 * cur + 2;
            const uint32* rqL = wq + (size_t)nl * (DIN / 4);
            const uint32* rqR = wq + (size_t)nr * (DIN / 4);
            la = rqL[lane]; lb = rqL[lane + 64]; lc = rqL[lane + 128];
            ra = rqR[lane]; rb = rqR[lane + 64]; rc = rqR[lane + 128];
            ls = wscale[nl]; rs = wscale[nr];
        }

        // ---- (2) int8 dot on resident regs ----
        float s0 = 0.f, s1 = 0.f, s2 = 0.f, s3 = 0.f;
        s0 = fmaf(xv0[0], sb0(a), s0); s1 = fmaf(xv0[1], sb1(a), s1);
        s2 = fmaf(xv0[2], sb2(a), s2); s3 = fmaf(xv0[3], sb3(a), s3);
        s0 = fmaf(xv1[0], sb0(b), s0); s1 = fmaf(xv1[1], sb1(b), s1);
        s2 = fmaf(xv1[2], sb2(b), s2); s3 = fmaf(xv1[3], sb3(b), s3);
        s0 = fmaf(xv2[0], sb0(c), s0); s1 = fmaf(xv2[1], sb1(c), s1);
        s2 = fmaf(xv2[2], sb2(c), s2); s3 = fmaf(xv2[3], sb3(c), s3);
        float part = ((s0 + s1) + (s2 + s3)) * s;
#pragma unroll
        for (int off = 32; off >= 1; off >>= 1) part += __shfl_xor(part, off);

        float lg    = part;
        bool  right = (part > 0.0f);

        // ---- (3) rare exact recheck (wave-uniform, ~5% of token-levels) ----
        if (fabsf(lg) < TAU) {
            const float4* wr = reinterpret_cast<const float4*>(w_in + (size_t)cur * DIN);
            const float4 w0 = wr[lane], w1 = wr[lane + 64], w2 = wr[lane + 128];
            double p0 = 0.0, p1 = 0.0, p2 = 0.0;
            p0 += (double)xv0[0] * w0.x; p0 += (double)xv0[1] * w0.y;
            p0 += (double)xv0[2] * w0.z; p0 += (double)xv0[3] * w0.w;
            p1 += (double)xv1[0] * w1.x; p1 += (double)xv1[1] * w1.y;
            p1 += (double)xv1[2] * w1.z; p1 += (double)xv1[3] * w1.w;
            p2 += (double)xv2[0] * w2.x; p2 += (double)xv2[1] * w2.y;
            p2 += (double)xv2[2] * w2.z; p2 += (double)xv2[3] * w2.w;
            double pd = (p0 + p1) + p2;
#pragma unroll
            for (int off = 32; off >= 1; off >>= 1) pd += __shfl_xor(pd, off);
            lg    = (float)pd;
            right = (pd > 0.0);
        }

        if (lane == 0)
            g_out[token * 12 + d] = 0.5f * lg * (1.0f + erff(lg * 0.7071067811865476f));

        // ---- (4) select prefetched child ----
        if (d < DEPTH) {
            a = right ? ra : la;
            b = right ? rb : lb;
            c = right ? rc : lc;
            s = right ? rs : ls;
            mask |= (right ? 1u : 0u) << d;
            cur = __builtin_amdgcn_readfirstlane(2 * cur + 1 + (right ? 1 : 0));
        }
    }
    if (lane == 0) bits_out[token] = mask;
}

// ---------------------------------------------------------------------------
// Gather kernel (int8, L2-resident): touches ONLY wTq (3.07 MB -> fits L2).
// Path reconstructed from decision bits; 36 fully independent dword loads.
// Output written with nontemporal stores. Axpy order identical to round 8.
// ---------------------------------------------------------------------------
__global__ __launch_bounds__(256) void fff_gather_i8(const uint32* __restrict__ wTq,
                                                     const unsigned* __restrict__ bits_in,
                                                     const float* __restrict__ g_in,
                                                     float* __restrict__ out) {
    const int token = (int)((blockIdx.x * blockDim.x + threadIdx.x) >> 6);
    const int lane  = (int)(threadIdx.x & 63);

    const unsigned mask = bits_in[token];
    float gv = 0.f;
    if (lane < 12) gv = g_in[token * 12 + lane];

    float acc[12];
#pragma unroll
    for (int i = 0; i < 12; ++i) acc[i] = 0.f;

    int cur = 0;
#pragma unroll
    for (int d = 0; d <= DEPTH; ++d) {
        const float gg = __shfl(gv, d);
        const float cf = gg * WT_STEP;
        const uint32* rt = wTq + (size_t)cur * (DIN / 4);
        const uint32 ta = rt[lane], tb = rt[lane + 64], tc = rt[lane + 128];
        acc[0]  = fmaf(cf, sb0(ta), acc[0]);  acc[1]  = fmaf(cf, sb1(ta), acc[1]);
        acc[2]  = fmaf(cf, sb2(ta), acc[2]);  acc[3]  = fmaf(cf, sb3(ta), acc[3]);
        acc[4]  = fmaf(cf, sb0(tb), acc[4]);  acc[5]  = fmaf(cf, sb1(tb), acc[5]);
        acc[6]  = fmaf(cf, sb2(tb), acc[6]);  acc[7]  = fmaf(cf, sb3(tb), acc[7]);
        acc[8]  = fmaf(cf, sb0(tc), acc[8]);  acc[9]  = fmaf(cf, sb1(tc), acc[9]);
        acc[10] = fmaf(cf, sb2(tc), acc[10]); acc[11] = fmaf(cf, sb3(tc), acc[11]);
        if (d < DEPTH) cur = 2 * cur + 1 + (int)((mask >> d) & 1u);
    }

    f32x4* orow = reinterpret_cast<f32x4*>(out + (size_t)token * DIN);
    f32x4 o0, o1, o2;
    o0[0] = acc[0];  o0[1] = acc[1];  o0[2] = acc[2];  o0[3] = acc[3];
    o1[0] = acc[4];  o1[1] = acc[5];  o1[2] = acc[6];  o1[3] = acc[7];
    o2[0] = acc[8];  o2[1] = acc[9];  o2[2] = acc[10]; o2[3] = acc[11];
    __builtin_nontemporal_store(o0, orow + lane);
    __builtin_nontemporal_store(o1, orow + lane + 64);
    __builtin_nontemporal_store(o2, orow + lane + 128);
}

// ---------------------------------------------------------------------------
// Fallback (ws too small): fused f32 kernel with strided w_out reads.
// ---------------------------------------------------------------------------
__global__ __launch_bounds__(256) void fff_fused_fallback(const float* __restrict__ x,
                                                          const float* __restrict__ w_in,
                                                          const float* __restrict__ w_o,
                                                          float* __restrict__ out) {
    const int token = (int)((blockIdx.x * blockDim.x + threadIdx.x) >> 6);
    const int lane  = (int)(threadIdx.x & 63);

    const float4* xr = reinterpret_cast<const float4*>(x + (size_t)token * DIN);
    float4 xv[3];
#pragma unroll
    for (int k = 0; k < 3; ++k) xv[k] = xr[lane + 64 * k];
    float4 acc[3];
#pragma unroll
    for (int k = 0; k < 3; ++k) acc[k] = make_float4(0.f, 0.f, 0.f, 0.f);

    int cur = 0;
#pragma unroll
    for (int d = 0; d <= DEPTH; ++d) {
        const float4* wr = reinterpret_cast<const float4*>(w_in + (size_t)cur * DIN);
        double part = 0.0;
#pragma unroll
        for (int k = 0; k < 3; ++k) {
            const float4 w = wr[lane + 64 * k];
            part += (double)xv[k].x * w.x; part += (double)xv[k].y * w.y;
            part += (double)xv[k].z * w.z; part += (double)xv[k].w * w.w;
        }
#pragma unroll
        for (int off = 32; off >= 1; off >>= 1) part += __shfl_xor(part, off);
        const float logit = (float)part;
        const float gg = 0.5f * logit * (1.0f + erff(logit * 0.7071067811865476f));
#pragma unroll
        for (int k = 0; k < 3; ++k) {
            const int j = (lane + 64 * k) * 4;
            acc[k].x = fmaf(gg, w_o[(size_t)(j + 0) * NNODES + cur], acc[k].x);
            acc[k].y = fmaf(gg, w_o[(size_t)(j + 1) * NNODES + cur], acc[k].y);
            acc[k].z = fmaf(gg, w_o[(size_t)(j + 2) * NNODES + cur], acc[k].z);
            acc[k].w = fmaf(gg, w_o[(size_t)(j + 3) * NNODES + cur], acc[k].w);
        }
        if (d < DEPTH) cur = 2 * cur + 1 + (part > 0.0 ? 1 : 0);
    }
    float4* orow = reinterpret_cast<float4*>(out + (size_t)token * DIN);
#pragma unroll
    for (int k = 0; k < 3; ++k) orow[lane + 64 * k] = acc[k];
}

extern "C" void kernel_launch(void* const* d_in, const int* in_sizes, int n_in,
                              void* d_out, int out_size, void* d_ws, size_t ws_size,
                              hipStream_t stream) {
    const float* x     = (const float*)d_in[0];   // [8192, 768]
    const float* w_in  = (const float*)d_in[1];   // [4095, 768]
    const float* w_out = (const float*)d_in[2];   // [768, 4095]
    float*       out   = (float*)d_out;           // [8192, 768]

    const size_t wq_bytes   = (size_t)NNODES * DIN;            // 3,144,960
    const size_t wTq_bytes  = (size_t)NNODES * DIN;            // 3,144,960
    const size_t sc_bytes   = ((size_t)NNODES * sizeof(float) + 255) & ~255ull;
    const size_t g_bytes    = (size_t)NTOK * 12 * sizeof(float);   // 393,216
    const size_t bits_bytes = (size_t)NTOK * sizeof(unsigned);     //  32,768
    const size_t need = wq_bytes + wTq_bytes + sc_bytes + g_bytes + bits_bytes;

    if (ws_size >= need) {
        char* ws = (char*)d_ws;
        uint32*   wq     = (uint32*)ws;
        uint32*   wTq    = (uint32*)(ws + wq_bytes);
        float*    wscale = (float*)(ws + wq_bytes + wTq_bytes);
        float*    g      = (float*)(ws + wq_bytes + wTq_bytes + sc_bytes);
        unsigned* bits   = (unsigned*)(ws + wq_bytes + wTq_bytes + sc_bytes + g_bytes);

        hipLaunchKernelGGL(fff_prep, dim3(4096), dim3(256), 0, stream,
                           w_in, w_out, wq, wscale, wTq);
        hipLaunchKernelGGL(fff_walk_i8, dim3(NTOK / 4), dim3(256), 0, stream,
                           x, w_in, wq, wscale, bits, g);
        hipLaunchKernelGGL(fff_gather_i8, dim3(NTOK / 4), dim3(256), 0, stream,
                           wTq, bits, g, out);
    } else {
        hipLaunchKernelGGL(fff_fused_fallback, dim3(NTOK / 4), dim3(256), 0, stream,
                           x, w_in, w_out, out);
    }
}

// Round 11
// 38.916 us; speedup vs baseline: 1.0779x; 1.0779x over previous
//
#include <hip/hip_runtime.h>
#include <math.h>

#define DEPTH    11
#define NNODES   4095
#define DIN      768
#define NTOK     8192
#define TAU      0.06f            // exact-recheck threshold (~7.2 sigma of int8 dot err)
#define WT_MAX   0.12f            // fixed wT quant range (7.7 sigma of N(0,1/sqrt(4095)))
#define WT_STEP  (WT_MAX / 127.0f)

typedef unsigned int uint32;

// ---------------------------------------------------------------------------
// Fused prep: blocks [0,3072) transpose+quantize w_out -> wTq (int8, fixed
// scale); blocks [3072,4096) row-quantize w_in -> wq (int8) + wscale (f32).
// (unchanged from round 8 — proven)
// ---------------------------------------------------------------------------
__global__ __launch_bounds__(256) void fff_prep(const float* __restrict__ w_in,
                                                const float* __restrict__ w_out,
                                                uint32* __restrict__ wq,
                                                float* __restrict__ wscale,
                                                uint32* __restrict__ wTq) {
    __shared__ float tile[32][33];
    const int bid = blockIdx.x;
    const int tid = threadIdx.x;

    if (bid < 3072) {
        const int n0 = (bid & 127) * 32;   // node tile
        const int j0 = (bid >> 7) * 32;    // feature tile (24 tiles)
        const int tx = tid & 31, ty = tid >> 5;  // (32,8)
#pragma unroll
        for (int i = 0; i < 32; i += 8) {
            const int j = j0 + ty + i;
            const int n = n0 + tx;
            if (n < NNODES) tile[ty + i][tx] = w_out[(size_t)j * NNODES + n];
        }
        __syncthreads();
        const int nl = tid >> 3;           // 0..31 node within tile
        const int jq = (tid & 7) * 4;      // 0,4,..,28
        const int n  = n0 + nl;
        if (n < NNODES) {
            const float inv = 127.0f / WT_MAX;
            int q0 = __float2int_rn(fminf(fmaxf(tile[jq + 0][nl] * inv, -127.f), 127.f));
            int q1 = __float2int_rn(fminf(fmaxf(tile[jq + 1][nl] * inv, -127.f), 127.f));
            int q2 = __float2int_rn(fminf(fmaxf(tile[jq + 2][nl] * inv, -127.f), 127.f));
            int q3 = __float2int_rn(fminf(fmaxf(tile[jq + 3][nl] * inv, -127.f), 127.f));
            const uint32 pack = (uint32)(q0 & 0xFF) | ((uint32)(q1 & 0xFF) << 8) |
                                ((uint32)(q2 & 0xFF) << 16) | ((uint32)(q3 & 0xFF) << 24);
            wTq[((size_t)n * DIN + j0 + jq) >> 2] = pack;
        }
    } else {
        const int row  = ((bid - 3072) * 256 + tid) >> 6;
        const int lane = tid & 63;
        if (row < NNODES) {
            const float4* wr = reinterpret_cast<const float4*>(w_in + (size_t)row * DIN);
            const float4 a = wr[lane], b = wr[lane + 64], c = wr[lane + 128];
            float m = fmaxf(fabsf(a.x), fabsf(a.y));
            m = fmaxf(m, fmaxf(fabsf(a.z), fabsf(a.w)));
            m = fmaxf(m, fmaxf(fabsf(b.x), fabsf(b.y)));
            m = fmaxf(m, fmaxf(fabsf(b.z), fabsf(b.w)));
            m = fmaxf(m, fmaxf(fabsf(c.x), fabsf(c.y)));
            m = fmaxf(m, fmaxf(fabsf(c.z), fabsf(c.w)));
#pragma unroll
            for (int off = 32; off >= 1; off >>= 1) m = fmaxf(m, __shfl_xor(m, off));
            const float inv = (m > 0.f) ? (127.0f / m) : 0.f;
            const float s   = m * (1.0f / 127.0f);

            uint32* rq = wq + (size_t)row * (DIN / 4);
            const float4 v[3] = {a, b, c};
#pragma unroll
            for (int k = 0; k < 3; ++k) {
                int q0 = __float2int_rn(fminf(fmaxf(v[k].x * inv, -127.f), 127.f));
                int q1 = __float2int_rn(fminf(fmaxf(v[k].y * inv, -127.f), 127.f));
                int q2 = __float2int_rn(fminf(fmaxf(v[k].z * inv, -127.f), 127.f));
                int q3 = __float2int_rn(fminf(fmaxf(v[k].w * inv, -127.f), 127.f));
                rq[lane + 64 * k] = (uint32)(q0 & 0xFF) | ((uint32)(q1 & 0xFF) << 8) |
                                    ((uint32)(q2 & 0xFF) << 16) | ((uint32)(q3 & 0xFF) << 24);
            }
            if (lane == 0) wscale[row] = s;
        }
    }
}

__device__ __forceinline__ float sb0(uint32 u) { return (float)((int)(u << 24) >> 24); }
__device__ __forceinline__ float sb1(uint32 u) { return (float)((int)(u << 16) >> 24); }
__device__ __forceinline__ float sb2(uint32 u) { return (float)((int)(u <<  8) >> 24); }
__device__ __forceinline__ float sb3(uint32 u) { return (float)((int)u        >> 24); }

// ---------------------------------------------------------------------------
// Fused main v3: round-9 structure with the dual-child prefetch FORCED to
// issue before the dot. Round 9's VGPR=72 (vs expected ~95) showed the
// compiler sank the speculative loads into the select, putting the load
// latency back on the decide->dot chain. The memory-clobber asm +
// sched_barrier(0) pair pins the load ISSUE above the dot while letting the
// s_waitcnt land at the select (after ~600cy of dot/reduce/gelu compute).
// Numerics byte-identical to rounds 8/9 (absmax 4.88e-3 proven).
// ---------------------------------------------------------------------------
__global__ __launch_bounds__(256, 4) void fff_main_i8p(const float* __restrict__ x,
                                                       const float* __restrict__ w_in,
                                                       const uint32* __restrict__ wq,
                                                       const float* __restrict__ wscale,
                                                       const uint32* __restrict__ wTq,
                                                       float* __restrict__ out) {
    const int token = (int)((blockIdx.x * blockDim.x + threadIdx.x) >> 6);
    const int lane  = (int)(threadIdx.x & 63);

    // Lane owns elements 4*(lane+64k)+m, k=0..2, m=0..3 (matches packed bytes).
    const float4* xr = reinterpret_cast<const float4*>(x + (size_t)token * DIN);
    const float4 xv0 = xr[lane], xv1 = xr[lane + 64], xv2 = xr[lane + 128];

    float acc[12];
#pragma unroll
    for (int i = 0; i < 12; ++i) acc[i] = 0.f;

    // root row state (node 0): dot-row regs, scale, wTq regs
    int cur = 0;
    uint32 a = wq[lane], b = wq[lane + 64], c = wq[lane + 128];
    float  s = wscale[0];
    uint32 ta = wTq[lane], tb = wTq[lane + 64], tc = wTq[lane + 128];

#pragma unroll
    for (int d = 0; d <= DEPTH; ++d) {
        // ---- (1) prefetch BOTH children dot-rows + scales; FORCE early issue ----
        uint32 la = 0, lb = 0, lc = 0, ra = 0, rb = 0, rc = 0;
        float  ls = 0.f, rs = 0.f;
        if (d < DEPTH) {
            const int nl = 2 * cur + 1, nr = 2 * cur + 2;
            const uint32* rqL = wq + (size_t)nl * (DIN / 4);
            const uint32* rqR = wq + (size_t)nr * (DIN / 4);
            la = rqL[lane]; lb = rqL[lane + 64]; lc = rqL[lane + 128];
            ra = rqR[lane]; rb = rqR[lane + 64]; rc = rqR[lane + 128];
            ls = wscale[nl]; rs = wscale[nr];
        }
        // Pin: the loads above must ISSUE here (memory order), but no value
        // dependency is created, so the s_waitcnt stays at the select below.
        asm volatile("" ::: "memory");
        __builtin_amdgcn_sched_barrier(0);

        // ---- (2) int8 dot on resident regs ----
        float s0 = 0.f, s1 = 0.f, s2 = 0.f, s3 = 0.f;
        s0 = fmaf(xv0.x, sb0(a), s0); s1 = fmaf(xv0.y, sb1(a), s1);
        s2 = fmaf(xv0.z, sb2(a), s2); s3 = fmaf(xv0.w, sb3(a), s3);
        s0 = fmaf(xv1.x, sb0(b), s0); s1 = fmaf(xv1.y, sb1(b), s1);
        s2 = fmaf(xv1.z, sb2(b), s2); s3 = fmaf(xv1.w, sb3(b), s3);
        s0 = fmaf(xv2.x, sb0(c), s0); s1 = fmaf(xv2.y, sb1(c), s1);
        s2 = fmaf(xv2.z, sb2(c), s2); s3 = fmaf(xv2.w, sb3(c), s3);
        float part = ((s0 + s1) + (s2 + s3)) * s;
#pragma unroll
        for (int off = 32; off >= 1; off >>= 1) part += __shfl_xor(part, off);

        float lg    = part;
        bool  right = (part > 0.0f);

        // ---- (3) rare exact recheck (wave-uniform, ~4.8% of token-levels) ----
        if (fabsf(lg) < TAU) {
            const float4* wr = reinterpret_cast<const float4*>(w_in + (size_t)cur * DIN);
            const float4 w0 = wr[lane], w1 = wr[lane + 64], w2 = wr[lane + 128];
            double p0 = 0.0, p1 = 0.0, p2 = 0.0;
            p0 += (double)xv0.x * w0.x; p0 += (double)xv0.y * w0.y;
            p0 += (double)xv0.z * w0.z; p0 += (double)xv0.w * w0.w;
            p1 += (double)xv1.x * w1.x; p1 += (double)xv1.y * w1.y;
            p1 += (double)xv1.z * w1.z; p1 += (double)xv1.w * w1.w;
            p2 += (double)xv2.x * w2.x; p2 += (double)xv2.y * w2.y;
            p2 += (double)xv2.z * w2.z; p2 += (double)xv2.w * w2.w;
            double pd = (p0 + p1) + p2;
#pragma unroll
            for (int off = 32; off >= 1; off >>= 1) pd += __shfl_xor(pd, off);
            lg    = (float)pd;
            right = (pd > 0.0);
        }

        const float g  = 0.5f * lg * (1.0f + erff(lg * 0.7071067811865476f));
        const float cf = g * WT_STEP;

        // ---- (4) int8 axpy on resident wTq regs ----
        acc[0]  = fmaf(cf, sb0(ta), acc[0]);  acc[1]  = fmaf(cf, sb1(ta), acc[1]);
        acc[2]  = fmaf(cf, sb2(ta), acc[2]);  acc[3]  = fmaf(cf, sb3(ta), acc[3]);
        acc[4]  = fmaf(cf, sb0(tb), acc[4]);  acc[5]  = fmaf(cf, sb1(tb), acc[5]);
        acc[6]  = fmaf(cf, sb2(tb), acc[6]);  acc[7]  = fmaf(cf, sb3(tb), acc[7]);
        acc[8]  = fmaf(cf, sb0(tc), acc[8]);  acc[9]  = fmaf(cf, sb1(tc), acc[9]);
        acc[10] = fmaf(cf, sb2(tc), acc[10]); acc[11] = fmaf(cf, sb3(tc), acc[11]);

        // ---- (5) select prefetched child; issue wTq[next] (one level of slack) ----
        if (d < DEPTH) {
            a = right ? ra : la;
            b = right ? rb : lb;
            c = right ? rc : lc;
            s = right ? rs : ls;
            const int nxt = __builtin_amdgcn_readfirstlane(2 * cur + 1 + (right ? 1 : 0));
            const uint32* rt = wTq + (size_t)nxt * (DIN / 4);
            ta = rt[lane]; tb = rt[lane + 64]; tc = rt[lane + 128];
            cur = nxt;
            // Pin wTq issue here too (used only after next level's dot).
            asm volatile("" ::: "memory");
            __builtin_amdgcn_sched_barrier(0);
        }
    }

    float4* orow = reinterpret_cast<float4*>(out + (size_t)token * DIN);
    orow[lane]       = make_float4(acc[0], acc[1], acc[2],  acc[3]);
    orow[lane + 64]  = make_float4(acc[4], acc[5], acc[6],  acc[7]);
    orow[lane + 128] = make_float4(acc[8], acc[9], acc[10], acc[11]);
}

// ---------------------------------------------------------------------------
// Fallback (ws too small): fused f32 kernel with strided w_out reads.
// ---------------------------------------------------------------------------
__global__ __launch_bounds__(256) void fff_fused_fallback(const float* __restrict__ x,
                                                          const float* __restrict__ w_in,
                                                          const float* __restrict__ w_o,
                                                          float* __restrict__ out) {
    const int token = (int)((blockIdx.x * blockDim.x + threadIdx.x) >> 6);
    const int lane  = (int)(threadIdx.x & 63);

    const float4* xr = reinterpret_cast<const float4*>(x + (size_t)token * DIN);
    float4 xv[3];
#pragma unroll
    for (int k = 0; k < 3; ++k) xv[k] = xr[lane + 64 * k];
    float4 acc[3];
#pragma unroll
    for (int k = 0; k < 3; ++k) acc[k] = make_float4(0.f, 0.f, 0.f, 0.f);

    int cur = 0;
#pragma unroll
    for (int d = 0; d <= DEPTH; ++d) {
        const float4* wr = reinterpret_cast<const float4*>(w_in + (size_t)cur * DIN);
        double part = 0.0;
#pragma unroll
        for (int k = 0; k < 3; ++k) {
            const float4 w = wr[lane + 64 * k];
            part += (double)xv[k].x * w.x; part += (double)xv[k].y * w.y;
            part += (double)xv[k].z * w.z; part += (double)xv[k].w * w.w;
        }
#pragma unroll
        for (int off = 32; off >= 1; off >>= 1) part += __shfl_xor(part, off);
        const float logit = (float)part;
        const float gg = 0.5f * logit * (1.0f + erff(logit * 0.7071067811865476f));
#pragma unroll
        for (int k = 0; k < 3; ++k) {
            const int j = (lane + 64 * k) * 4;
            acc[k].x = fmaf(gg, w_o[(size_t)(j + 0) * NNODES + cur], acc[k].x);
            acc[k].y = fmaf(gg, w_o[(size_t)(j + 1) * NNODES + cur], acc[k].y);
            acc[k].z = fmaf(gg, w_o[(size_t)(j + 2) * NNODES + cur], acc[k].z);
            acc[k].w = fmaf(gg, w_o[(size_t)(j + 3) * NNODES + cur], acc[k].w);
        }
        if (d < DEPTH) cur = 2 * cur + 1 + (part > 0.0 ? 1 : 0);
    }
    float4* orow = reinterpret_cast<float4*>(out + (size_t)token * DIN);
#pragma unroll
    for (int k = 0; k < 3; ++k) orow[lane + 64 * k] = acc[k];
}

extern "C" void kernel_launch(void* const* d_in, const int* in_sizes, int n_in,
                              void* d_out, int out_size, void* d_ws, size_t ws_size,
                              hipStream_t stream) {
    const float* x     = (const float*)d_in[0];   // [8192, 768]
    const float* w_in  = (const float*)d_in[1];   // [4095, 768]
    const float* w_out = (const float*)d_in[2];   // [768, 4095]
    float*       out   = (float*)d_out;           // [8192, 768]

    const size_t wq_bytes  = (size_t)NNODES * DIN;            // 3,144,960
    const size_t wTq_bytes = (size_t)NNODES * DIN;            // 3,144,960
    const size_t sc_bytes  = (size_t)NNODES * sizeof(float);  //    16,380
    const size_t need = wq_bytes + wTq_bytes + sc_bytes;      // ~6.3 MB

    if (ws_size >= need) {
        char* ws = (char*)d_ws;
        uint32* wq     = (uint32*)ws;
        uint32* wTq    = (uint32*)(ws + wq_bytes);
        float*  wscale = (float*)(ws + wq_bytes + wTq_bytes);

        hipLaunchKernelGGL(fff_prep, dim3(4096), dim3(256), 0, stream,
                           w_in, w_out, wq, wscale, wTq);
        hipLaunchKernelGGL(fff_main_i8p, dim3(NTOK / 4), dim3(256), 0, stream,
                           x, w_in, wq, wscale, wTq, out);
    } else {
        hipLaunchKernelGGL(fff_fused_fallback, dim3(NTOK / 4), dim3(256), 0, stream,
                           x, w_in, w_out, out);
    }
}